// Round 10
// baseline (202.459 us; speedup 1.0000x reference)
//
#include <hip/hip_runtime.h>
#include <hip/hip_fp16.h>

namespace {

constexpr int B = 128, N = 2048, E = 32768;
constexpr int LOG2N = 11, LOG2E = 15;
constexpr int QE = 8192;        // edges per quarter block
constexpr int RECCAP = 14336;   // QE + 3*2048 worst-case alignment padding
constexpr int SSTR = 16384;     // sorted stride per quarter block (entries)

// ws layout (bytes)
constexpr size_t OFF_H0  = 0;                     // B*N float4 = 4 MB
constexpr size_t OFF_H1  = 4u * 1024 * 1024;      // B*N float4 = 4 MB
constexpr size_t OFF_SRT = 8u * 1024 * 1024;      // 512 * SSTR u32 = 32 MB
constexpr size_t OFF_SEG = 40u * 1024 * 1024;     // 512 * N u32 = 4 MB

// Quarter-batch LDS counting sort (R6 winner structure), 4B packed records
// (src | f16(dt)<<16), segment starts PADDED to 4-record (16B) alignment so
// the layer kernel can consume 4 edges per global_load_dwordx4.
__global__ __launch_bounds__(1024) void sort_kernel(const int* __restrict__ edge_index,
                                                    const float* __restrict__ edge_time,
                                                    const float* __restrict__ timestamp,
                                                    unsigned* __restrict__ sorted,
                                                    unsigned* __restrict__ seg) {
  __shared__ int      cnt[N];        // 8 KB counts -> cursors
  __shared__ int      partial[1024]; // 4 KB
  __shared__ int      tot_s;
  __shared__ unsigned rec[RECCAP];   // 56 KB packed records => ~70 KB total
  int blk = blockIdx.x, b = blk >> 2, q = blk & 3, t = threadIdx.x;
  const int* src_arr = edge_index + ((size_t)(2 * b) << LOG2E) + q * QE;
  const int* dst_arr = edge_index + ((size_t)(2 * b + 1) << LOG2E) + q * QE;
  const float* et    = edge_time + ((size_t)b << LOG2E) + q * QE;
  float ts = timestamp[b];

  cnt[t] = 0; cnt[t + 1024] = 0;
  __syncthreads();

  for (int e = t; e < QE; e += 1024) atomicAdd(&cnt[dst_arr[e]], 1);
  __syncthreads();

  // exclusive scan of PADDED widths (2/thread)
  int i0 = 2 * t, i1 = 2 * t + 1;
  int d0 = cnt[i0], d1 = cnt[i1];
  int w0 = (d0 + 3) & ~3, w1 = (d1 + 3) & ~3;
  int sum = w0 + w1;
  partial[t] = sum;
  __syncthreads();
  for (int d = 1; d < 1024; d <<= 1) {
    int v = (t >= d) ? partial[t - d] : 0;
    __syncthreads();
    partial[t] += v;
    __syncthreads();
  }
  int run = partial[t] - sum;
  int run2 = run + w0;
  if (t == 1023) tot_s = partial[t];
  // seg descriptor: beg (16b, 4-aligned) | deg<<16
  unsigned* sg = seg + (size_t)blk * N;
  sg[i0] = (unsigned)run  | ((unsigned)d0 << 16);
  sg[i1] = (unsigned)run2 | ((unsigned)d1 << 16);
  cnt[i0] = run;   // cursor
  cnt[i1] = run2;
  __syncthreads();

  // scatter packed (src | f16(dt)<<16) into LDS CSR
  for (int e = t; e < QE; e += 1024) {
    int dst = dst_arr[e], src = src_arr[e];
    float dt = ts - et[e];
    unsigned hd = (unsigned)__half_as_ushort(__float2half(dt));
    int pos = atomicAdd(&cnt[dst], 1);
    rec[pos] = (unsigned)src | (hd << 16);
  }
  __syncthreads();

  // coalesced stream-out of used prefix (uint4 = 4 records); padding gaps
  // contain garbage but are masked by deg on the read side.
  int tot4 = tot_s >> 2;  // tot is 4-aligned
  const uint4* rec4 = (const uint4*)rec;
  uint4* out4 = (uint4*)(sorted + (size_t)blk * SSTR);
  for (int i = t; i < tot4; i += 1024) out4[i] = rec4[i];
}

// 8 blocks/batch x 256 thr. Thread t owns node oct*256+t; walks its 4
// quarter-segments in 4-edge chunks (one dwordx4 per chunk). The online-
// softmax carried chain advances 4 edges per link (R9 showed the layer is
// latency-chain-bound: occupancy 4x -> no change; chain depth is the knob).
__global__ __launch_bounds__(256) void layer_kernel(const float4* __restrict__ h_in,
                                                    float4* __restrict__ h_out,
                                                    const unsigned* __restrict__ seg,
                                                    const unsigned* __restrict__ sorted,
                                                    const float* __restrict__ tw,
                                                    const float* __restrict__ tb,
                                                    const float* __restrict__ Wq,
                                                    const float* __restrict__ Wk,
                                                    const float* __restrict__ Wv,
                                                    const float* __restrict__ Wo,
                                                    const float* __restrict__ bo) {
  __shared__ float4 lh[N];  // 32 KB, node-indexed
  int blk = blockIdx.x, b = blk >> 3, oct = blk & 7, t = threadIdx.x;

  const float4* hb = h_in + ((size_t)b << LOG2N);
#pragma unroll
  for (int j = 0; j < 8; j++) {
    int idx = j * 256 + t;
    lh[idx] = hb[idx];
  }

  float twf[4], tbf[4], bof[4], wq[16], wof[16], wk[32], wv[32];
#pragma unroll
  for (int j = 0; j < 4; j++) { twf[j] = tw[j]; tbf[j] = tb[j]; bof[j] = bo[j]; }
#pragma unroll
  for (int j = 0; j < 16; j++) { wq[j] = Wq[j]; wof[j] = Wo[j]; }
#pragma unroll
  for (int j = 0; j < 32; j++) { wk[j] = Wk[j]; wv[j] = Wv[j]; }
  __syncthreads();

  int n = (oct << 8) + t;
  float4 hn = lh[n];
  float q0 = hn.x * wq[0] + hn.y * wq[4] + hn.z * wq[8]  + hn.w * wq[12];
  float q1 = hn.x * wq[1] + hn.y * wq[5] + hn.z * wq[9]  + hn.w * wq[13];
  float q2 = hn.x * wq[2] + hn.y * wq[6] + hn.z * wq[10] + hn.w * wq[14];
  float q3 = hn.x * wq[3] + hn.y * wq[7] + hn.z * wq[11] + hn.w * wq[15];
  const float RS2 = 0.70710678118654752f;
  float u0[8], u1[8];
#pragma unroll
  for (int j = 0; j < 8; j++) {
    u0[j] = RS2 * (q0 * wk[j * 4 + 0] + q1 * wk[j * 4 + 1]);
    u1[j] = RS2 * (q2 * wk[j * 4 + 2] + q3 * wk[j * 4 + 3]);
  }

  // prefetch all 4 segment descriptors + first chunks (8 independent loads)
  int begq[4], degq[4];
  const uint4* sp[4];
#pragma unroll
  for (int q = 0; q < 4; ++q) {
    int qblk = (b << 2) + q;
    unsigned sd = seg[(size_t)qblk * N + n];
    begq[q] = (int)(sd & 0xFFFFu);
    degq[q] = (int)(sd >> 16);
    sp[q] = (const uint4*)(sorted + (size_t)qblk * SSTR + begq[q]);
  }
  uint4 pf[4];
#pragma unroll
  for (int q = 0; q < 4; ++q)
    pf[q] = (degq[q] > 0) ? sp[q][0] : make_uint4(0, 0, 0, 0);

  float m0 = -INFINITY, m1 = -INFINITY;
  float s0 = 0.f, s1 = 0.f, a00 = 0.f, a01 = 0.f, a10 = 0.f, a11 = 0.f;

#pragma unroll
  for (int q = 0; q < 4; ++q) {
    int dg = degq[q];
    if (dg <= 0) continue;
    int nch = (dg + 3) >> 2;
    uint4 cur = pf[q];
    for (int c = 0; c < nch; ++c) {
      uint4 nxt = (c + 1 < nch) ? sp[q][c + 1] : make_uint4(0, 0, 0, 0);
      unsigned rcs[4] = {cur.x, cur.y, cur.z, cur.w};
      int jb = c << 2;
      float l0e[4], l1e[4], v0e[4], v1e[4], v2e[4], v3e[4];
#pragma unroll
      for (int i = 0; i < 4; ++i) {
        bool valid = (jb + i) < dg;
        unsigned rcv = valid ? rcs[i] : 0u;
        int src = (int)(rcv & 0x7FFu);   // src < 2048 always (11 bits)
        float dt = __half2float(__ushort_as_half((unsigned short)(rcv >> 16)));
        float4 hs = lh[src];
        float p0c = __cosf(dt * twf[0] + tbf[0]);
        float p1c = __cosf(dt * twf[1] + tbf[1]);
        float p2c = __cosf(dt * twf[2] + tbf[2]);
        float p3c = __cosf(dt * twf[3] + tbf[3]);
        float l0 = u0[0] * hs.x + u0[1] * hs.y + u0[2] * hs.z + u0[3] * hs.w
                 + u0[4] * p0c + u0[5] * p1c + u0[6] * p2c + u0[7] * p3c;
        float l1 = u1[0] * hs.x + u1[1] * hs.y + u1[2] * hs.z + u1[3] * hs.w
                 + u1[4] * p0c + u1[5] * p1c + u1[6] * p2c + u1[7] * p3c;
        l0e[i] = valid ? l0 : -INFINITY;
        l1e[i] = valid ? l1 : -INFINITY;
        v0e[i] = wv[0] * hs.x + wv[4] * hs.y + wv[8]  * hs.z + wv[12] * hs.w
               + wv[16] * p0c + wv[20] * p1c + wv[24] * p2c + wv[28] * p3c;
        v1e[i] = wv[1] * hs.x + wv[5] * hs.y + wv[9]  * hs.z + wv[13] * hs.w
               + wv[17] * p0c + wv[21] * p1c + wv[25] * p2c + wv[29] * p3c;
        v2e[i] = wv[2] * hs.x + wv[6] * hs.y + wv[10] * hs.z + wv[14] * hs.w
               + wv[18] * p0c + wv[22] * p1c + wv[26] * p2c + wv[30] * p3c;
        v3e[i] = wv[3] * hs.x + wv[7] * hs.y + wv[11] * hs.z + wv[15] * hs.w
               + wv[19] * p0c + wv[23] * p1c + wv[27] * p2c + wv[31] * p3c;
      }
      // fold 4 edges into online softmax: one carried exp-link per CHUNK
      float lx0 = fmaxf(fmaxf(l0e[0], l0e[1]), fmaxf(l0e[2], l0e[3]));
      float nm0 = fmaxf(m0, lx0);
      float sc0 = __expf(m0 - nm0);
      float pe0 = __expf(l0e[0] - nm0), pe1 = __expf(l0e[1] - nm0);
      float pe2 = __expf(l0e[2] - nm0), pe3 = __expf(l0e[3] - nm0);
      s0  = s0  * sc0 + (pe0 + pe1 + pe2 + pe3);
      a00 = a00 * sc0 + (pe0 * v0e[0] + pe1 * v0e[1] + pe2 * v0e[2] + pe3 * v0e[3]);
      a01 = a01 * sc0 + (pe0 * v1e[0] + pe1 * v1e[1] + pe2 * v1e[2] + pe3 * v1e[3]);
      m0 = nm0;
      float lx1 = fmaxf(fmaxf(l1e[0], l1e[1]), fmaxf(l1e[2], l1e[3]));
      float nm1 = fmaxf(m1, lx1);
      float sc1 = __expf(m1 - nm1);
      float qe0 = __expf(l1e[0] - nm1), qe1 = __expf(l1e[1] - nm1);
      float qe2 = __expf(l1e[2] - nm1), qe3 = __expf(l1e[3] - nm1);
      s1  = s1  * sc1 + (qe0 + qe1 + qe2 + qe3);
      a10 = a10 * sc1 + (qe0 * v2e[0] + qe1 * v2e[1] + qe2 * v2e[2] + qe3 * v2e[3]);
      a11 = a11 * sc1 + (qe0 * v3e[0] + qe1 * v3e[1] + qe2 * v3e[2] + qe3 * v3e[3]);
      m1 = nm1;
      cur = nxt;
    }
  }
  float d0 = (s0 == 0.f) ? 1.f : s0;
  float d1 = (s1 == 0.f) ? 1.f : s1;
  float at0 = a00 / d0, at1 = a01 / d0, at2 = a10 / d1, at3 = a11 / d1;
  float o0 = bof[0] + at0 * wof[0] + at1 * wof[4] + at2 * wof[8]  + at3 * wof[12];
  float o1 = bof[1] + at0 * wof[1] + at1 * wof[5] + at2 * wof[9]  + at3 * wof[13];
  float o2 = bof[2] + at0 * wof[2] + at1 * wof[6] + at2 * wof[10] + at3 * wof[14];
  float o3 = bof[3] + at0 * wof[3] + at1 * wof[7] + at2 * wof[11] + at3 * wof[15];
  h_out[((size_t)b << LOG2N) + n] =
      make_float4(fmaxf(hn.x + o0, 0.f), fmaxf(hn.y + o1, 0.f),
                  fmaxf(hn.z + o2, 0.f), fmaxf(hn.w + o3, 0.f));
}

__global__ void final_kernel(const float4* __restrict__ h,
                             const int* __restrict__ src_index, const int* __restrict__ dst_index,
                             const float* __restrict__ timestamp,
                             const float* __restrict__ tw,
                             const float* __restrict__ tb,
                             const float* __restrict__ W_lin,
                             const float* __restrict__ b_lin,
                             float* __restrict__ out) {
  int b = threadIdx.x;
  if (b >= B) return;
  float4 sx = h[(((size_t)b) << LOG2N) + src_index[b]];
  float4 dx = h[(((size_t)b) << LOG2N) + dst_index[b]];
  float ts = timestamp[b];
  float f[12];
  f[0] = sx.x; f[1] = sx.y; f[2] = sx.z; f[3] = sx.w;
  f[4] = dx.x; f[5] = dx.y; f[6] = dx.z; f[7] = dx.w;
#pragma unroll
  for (int j = 0; j < 4; j++) f[8 + j] = __cosf(ts * tw[j] + tb[j]);
#pragma unroll
  for (int c = 0; c < 2; c++) {
    float o = b_lin[c];
#pragma unroll
    for (int j = 0; j < 12; j++) o += f[j] * W_lin[j * 2 + c];
    out[b * 2 + c] = o;
  }
}

}  // namespace

extern "C" void kernel_launch(void* const* d_in, const int* in_sizes, int n_in,
                              void* d_out, int out_size, void* d_ws, size_t ws_size,
                              hipStream_t stream) {
  (void)in_sizes; (void)n_in; (void)out_size; (void)ws_size;
  const float* x         = (const float*)d_in[0];
  const int*   edge_idx  = (const int*)d_in[1];
  const float* edge_time = (const float*)d_in[2];
  const float* timestamp = (const float*)d_in[3];
  const int*   src_index = (const int*)d_in[4];
  const int*   dst_index = (const int*)d_in[5];
  const float* time_w    = (const float*)d_in[6];
  const float* time_b    = (const float*)d_in[7];
  const float* Wq        = (const float*)d_in[8];
  const float* Wk        = (const float*)d_in[9];
  const float* Wv        = (const float*)d_in[10];
  const float* Wo        = (const float*)d_in[11];
  const float* bo        = (const float*)d_in[12];
  const float* W_lin     = (const float*)d_in[13];
  const float* b_lin     = (const float*)d_in[14];

  char* ws = (char*)d_ws;
  float4*   h0     = (float4*)(ws + OFF_H0);
  float4*   h1     = (float4*)(ws + OFF_H1);
  unsigned* sorted = (unsigned*)(ws + OFF_SRT);
  unsigned* seg    = (unsigned*)(ws + OFF_SEG);

  sort_kernel<<<4 * B, 1024, 0, stream>>>(edge_idx, edge_time, timestamp, sorted, seg);

  layer_kernel<<<8 * B, 256, 0, stream>>>((const float4*)x, h1, seg, sorted,
                                          time_w, time_b,
                                          Wq + 0 * 16, Wk + 0 * 32, Wv + 0 * 32,
                                          Wo + 0 * 16, bo + 0 * 4);
  layer_kernel<<<8 * B, 256, 0, stream>>>(h1, h0, seg, sorted,
                                          time_w, time_b,
                                          Wq + 1 * 16, Wk + 1 * 32, Wv + 1 * 32,
                                          Wo + 1 * 16, bo + 1 * 4);

  final_kernel<<<1, 128, 0, stream>>>(h0, src_index, dst_index, timestamp, time_w, time_b,
                                      W_lin, b_lin, (float*)d_out);
}